// Round 7
// baseline (617.088 us; speedup 1.0000x reference)
//
#include <hip/hip_runtime.h>
#include <stdint.h>

#define AS1 __attribute__((address_space(1)))
#define AS3 __attribute__((address_space(3)))

typedef short v8s  __attribute__((ext_vector_type(8)));
typedef float v4f  __attribute__((ext_vector_type(4)));
typedef float v16f __attribute__((ext_vector_type(16)));

#define C_IN  512
#define C_OUT 512
#define HW    64
#define COEF  9.20711955e-04f   // 1 / (16 * sqrt(9*512))

// E ws: [pu(2)][ocb(16)][ph(32)] chunks of [tap(18)][oc(32)][slot(2)]x16B = 18432 B
#define E_PH_SHORTS 9216
#define E_WS_BYTES  (2u*16u*32u*18432u)               // 18,874,368
// x ws: [n(8)][hp(66)][wp(66)][512 ic], per-(hp,wp): [ph(32)][slot(2)][8 ic] bf16
#define XT_BYTES    ((size_t)8*66*66*512*2)           // 35,684,352
#define WS_NEED     ((size_t)E_WS_BYTES + XT_BYTES)

// LDS: 2 half-buffers of { E [18][32][2]x16B = 18432 | x [18 rows][34 cols][2]x16B = 19584 }
#define HALF      38016
#define XOFF      18432
#define LDS_BYTES (2*HALF)   // 76032

__device__ __forceinline__ float Gf(int i) {
    return (i < 0 || i > 3) ? 0.f : ((i == 1 || i == 2) ? 3.f : 1.f);
}
__device__ __forceinline__ short f2bf(float f) {
    uint32_t u = __float_as_uint(f);
    u += 0x7fffu + ((u >> 16) & 1u);
    return (short)(u >> 16);
}

// ---------------- precompute: x -> padded NHWC bf16 via LDS transpose ----------
// per-(hp,wp) 512-ic layout: phase ph owns 32B (2 slots of 8 ic); physical slot s
// holds ic-group (s ^ ((wp>>2)&1)) — 1-bit source-side swizzle.
__global__ __launch_bounds__(256) void xpose_kernel(const float* __restrict__ x,
                                                    short* __restrict__ xt) {
    const int b     = blockIdx.x;
    const int icb64 = b & 7;
    const int hp    = (b >> 3) % 66;
    const int n     = (b >> 3) / 66;
    const int t     = threadIdx.x;

    __shared__ short tile[64][80];   // [w][ic_local]

    const bool hvalid = (hp >= 1 && hp <= 64);
    if (hvalid) {
        #pragma unroll
        for (int r = 0; r < 4; ++r) {
            const int i  = (t >> 4) + r * 16;     // ic_local 0..63
            const int w0 = (t & 15) * 4;          // w 0..63
            const float* src = x + ((size_t)(n * C_IN + icb64 * 64 + i) * HW + (hp - 1)) * HW + w0;
            float4 v = *(const float4*)src;
            tile[w0 + 0][i] = f2bf(v.x);
            tile[w0 + 1][i] = f2bf(v.y);
            tile[w0 + 2][i] = f2bf(v.z);
            tile[w0 + 3][i] = f2bf(v.w);
        }
    }
    __syncthreads();

    // 66 wp x 8 units (4 local phases x 2 slots) = 528 units of 16B
    for (int u = t; u < 528; u += 256) {
        const int wp   = u >> 3;
        const int gs   = u & 7;
        const int lph  = gs >> 1;
        const int slot = gs & 1;
        v8s o = (v8s)0;
        if (hvalid && wp >= 1 && wp <= 64) {
            const int glog = slot ^ ((wp >> 2) & 1);
            const int il   = lph * 16 + glog * 8;
            o = *(const v8s*)&tile[wp - 1][il];
        }
        *(v8s*)(xt + ((size_t)(n * 66 + hp) * 66 + wp) * 512
                   + (icb64 * 4 + lph) * 16 + slot * 8) = o;
    }
}

// ---------------- precompute: E image, 16-ic phase chunks, bf16, swizzled -------
__global__ __launch_bounds__(256) void prep_e_kernel(const float* __restrict__ w,
                                                     short* __restrict__ ews) {
    int u = blockIdx.x * 256 + threadIdx.x;   // 1,179,648 units of 16B
    int slot = u & 1;
    int oc_l = (u >> 1) & 31;
    int tap  = (u >> 6) % 18;
    int rest = (u >> 6) / 18;                  // ph + 32*(ocb + 16*pu)
    int ph   = rest & 31;
    int ocb  = (rest >> 5) & 15;
    int pu   = rest >> 9;
    int pv   = tap & 1;
    int ts   = tap >> 1;
    int tt   = ts / 3, ss = ts - tt * 3;
    int m    = 2 * tt + 1 - pu;
    int nn   = 2 * ss + 1 - pv;
    int glog = slot ^ ((oc_l >> 2) & 1);
    int ic0  = ph * 16 + glog * 8;
    int oc   = ocb * 32 + oc_l;

    v8s o;
    #pragma unroll
    for (int j = 0; j < 8; ++j) {
        float acc = 0.f;
        #pragma unroll
        for (int p = 0; p < 3; ++p) {
            float gm = Gf(m - p);
            if (gm != 0.f) {
                #pragma unroll
                for (int q = 0; q < 3; ++q) {
                    float gn = Gf(nn - q);
                    if (gn != 0.f)
                        acc += gm * gn * w[((size_t)(p * 3 + q) * C_IN + ic0 + j) * C_OUT + oc];
                }
            }
        }
        o[j] = f2bf(acc * COEF);
    }
    *(v8s*)(ews + (size_t)u * 8) = o;
}

// ---------------- main MFMA kernel (32x32x16, counted-vmcnt pipeline) -----------
__global__ __launch_bounds__(256, 2) void conv_mfma_kernel(const short* __restrict__ xt,
                                                           const short* __restrict__ ews,
                                                           float* __restrict__ out) {
    int bid  = blockIdx.x;
    int wgid = (bid & 7) * 256 + (bid >> 3);   // bijective XCD swizzle (2048 % 8 == 0)
    int vhb = wgid & 1;  wgid >>= 1;
    int uhb = wgid & 3;  wgid >>= 2;
    int n   = wgid & 7;  wgid >>= 3;
    int ocb = wgid & 15; wgid >>= 4;
    int pu  = wgid;
    const int uh0 = uhb * 16, vh0 = vhb * 32;

    __shared__ char lds_raw[LDS_BYTES];
    AS3 char* lds3 = (AS3 char*)lds_raw;

    const int tid  = threadIdx.x;
    const int lane = tid & 63;
    const int wid  = tid >> 6;      // wave's uh-quarter (0..3)
    const int l31  = lane & 31;
    const int hi   = lane >> 5;

    // ---- staging setup: every wave issues EXACTLY 10 global_load_lds per phase ----
    // units: 0..1151 = E (its 0-3 full + it4 waves 0,1); 1152..2375 = x
    // (it4 waves 2,3 + its 5-8 full + it9 lanes 0..17 of every wave)
    const short* eb0 = ews + (size_t)((pu * 16 + ocb) * 32) * E_PH_SHORTS + (size_t)tid * 8;

    const short* xp[6];
    int xdst[6];
    #pragma unroll
    for (int it2 = 0; it2 < 6; ++it2) {
        int j;
        if (it2 == 5) j = (lane < 18) ? (1152 + wid * 18 + lane) : 0;
        else          j = (it2 + 4) * 256 + tid - 1152;
        if (j < 0) j = 0;
        const int row = j / 68;
        const int rr  = j - row * 68;
        const int col = rr >> 1;
        const int slt = rr & 1;
        xp[it2]   = xt + ((size_t)(n * 66 + uh0 + row) * 66 + (vh0 + col)) * 512 + slt * 8;
        xdst[it2] = XOFF + j * 16;
    }

#define STAGE(bufoff, ph_) do {                                                       \
    const short* ebp_ = eb0 + (size_t)(ph_) * E_PH_SHORTS;                            \
    _Pragma("unroll")                                                                 \
    for (int it_ = 0; it_ < 4; ++it_)                                                 \
        __builtin_amdgcn_global_load_lds((const AS1 void*)(ebp_ + it_ * 2048),        \
            (AS3 void*)(lds3 + (bufoff) + it_ * 4096 + tid * 16), 16, 0, 0);          \
    if (tid < 128)                                                                    \
        __builtin_amdgcn_global_load_lds((const AS1 void*)(ebp_ + 4 * 2048),          \
            (AS3 void*)(lds3 + (bufoff) + 4 * 4096 + tid * 16), 16, 0, 0);            \
    else                                                                              \
        __builtin_amdgcn_global_load_lds((const AS1 void*)(xp[0] + (ph_) * 16),       \
            (AS3 void*)(lds3 + (bufoff) + xdst[0]), 16, 0, 0);                        \
    _Pragma("unroll")                                                                 \
    for (int it2_ = 1; it2_ < 5; ++it2_)                                              \
        __builtin_amdgcn_global_load_lds((const AS1 void*)(xp[it2_] + (ph_) * 16),    \
            (AS3 void*)(lds3 + (bufoff) + xdst[it2_]), 16, 0, 0);                     \
    if (lane < 18)                                                                    \
        __builtin_amdgcn_global_load_lds((const AS1 void*)(xp[5] + (ph_) * 16),       \
            (AS3 void*)(lds3 + (bufoff) + xdst[5]), 16, 0, 0);                        \
} while (0)

#define PIPE_WAIT(N) do {                                                             \
    asm volatile("s_waitcnt vmcnt(" #N ")" ::: "memory");                             \
    __builtin_amdgcn_sched_barrier(0);                                                \
    __builtin_amdgcn_s_barrier();                                                     \
    __builtin_amdgcn_sched_barrier(0);                                                \
} while (0)

#define PIPE_POST() do {                                                              \
    __builtin_amdgcn_sched_barrier(0);                                                \
    __builtin_amdgcn_s_barrier();                                                     \
    __builtin_amdgcn_sched_barrier(0);                                                \
} while (0)

    v16f acc[4][2];   // [u][pv]
    #pragma unroll
    for (int u = 0; u < 4; ++u)
        #pragma unroll
        for (int pv = 0; pv < 2; ++pv)
            acc[u][pv] = (v16f)0.f;

    const int sae = (hi ^ ((l31 >> 2) & 1)) * 16;    // B slot swizzle (oc_l == l31)

#define COMPUTE(bufoff) do {                                                          \
    const char* eb_ = lds_raw + (bufoff);                                             \
    const char* xb_ = lds_raw + (bufoff) + XOFF;                                      \
    _Pragma("unroll")                                                                 \
    for (int s_ = 0; s_ < 3; ++s_) {                                                  \
        const int c_  = l31 + s_;                                                     \
        const int sa_ = (hi ^ ((c_ >> 2) & 1)) * 16;                                  \
        v8s A_[6];                                                                    \
        _Pragma("unroll")                                                             \
        for (int rr_ = 0; rr_ < 6; ++rr_)                                             \
            A_[rr_] = *(const v8s*)(xb_ + ((wid * 4 + rr_) * 34 + c_) * 32 + sa_);    \
        v8s B_[6];                                                                    \
        _Pragma("unroll")                                                             \
        for (int t_ = 0; t_ < 3; ++t_)                                                \
            _Pragma("unroll")                                                         \
            for (int pv_ = 0; pv_ < 2; ++pv_)                                         \
                B_[t_ * 2 + pv_] = *(const v8s*)(eb_ + ((t_ * 3 + s_) * 2 + pv_) * 1024 \
                                                 + l31 * 32 + sae);                   \
        __builtin_amdgcn_s_setprio(1);                                                \
        _Pragma("unroll")                                                             \
        for (int t_ = 0; t_ < 3; ++t_)                                                \
            _Pragma("unroll")                                                         \
            for (int pv_ = 0; pv_ < 2; ++pv_)                                         \
                _Pragma("unroll")                                                     \
                for (int u_ = 0; u_ < 4; ++u_)                                        \
                    acc[u_][pv_] = __builtin_amdgcn_mfma_f32_32x32x16_bf16(           \
                        A_[u_ + t_], B_[t_ * 2 + pv_], acc[u_][pv_], 0, 0, 0);        \
        __builtin_amdgcn_s_setprio(0);                                                \
    }                                                                                 \
} while (0)

    // ---- pipelined main loop: 32 phases of 16 ic ----
    STAGE(0, 0);
    #pragma unroll 1
    for (int k = 0; k < 15; ++k) {
        const int ph = 2 * k;
        STAGE(HALF, ph + 1); PIPE_WAIT(10); COMPUTE(0);    PIPE_POST();
        STAGE(0,    ph + 2); PIPE_WAIT(10); COMPUTE(HALF); PIPE_POST();
    }
    STAGE(HALF, 31); PIPE_WAIT(10); COMPUTE(0); PIPE_POST();
    PIPE_WAIT(0);    COMPUTE(HALF);

#undef STAGE
#undef PIPE_WAIT
#undef PIPE_POST
#undef COMPUTE

    // epilogue: D col = lane&31 (oc), row = (reg&3) + 8*(reg>>2) + 4*(lane>>5) (vh)
    const int oc_g = ocb * 32 + l31;
    float* ob = out + ((size_t)(n * C_OUT + oc_g)) * 128 * 128;
    #pragma unroll
    for (int u = 0; u < 4; ++u) {
        const int h = 2 * (uh0 + wid * 4 + u) + pu;
        #pragma unroll
        for (int rg = 0; rg < 8; ++rg) {
            const int reg  = rg * 2;
            const int vh_l = (reg & 3) + 8 * (reg >> 2) + 4 * hi;
            v4f f;
            f[0] = acc[u][0][reg];
            f[1] = acc[u][1][reg];
            f[2] = acc[u][0][reg + 1];
            f[3] = acc[u][1][reg + 1];
            *(v4f*)(ob + (size_t)h * 128 + 2 * (vh0 + vh_l)) = f;
        }
    }
}

// ---------------- fallback (validated round-1 VALU kernel) ----------------------
#define ICB 8
#define UB  4
__global__ __launch_bounds__(256) void conv_par_kernel(
        const float* __restrict__ x, const float* __restrict__ w,
        float* __restrict__ out) {
    const int octile = blockIdx.x;
    const int n      = blockIdx.y >> 4;
    const int uhb    = blockIdx.y & 15;
    const int pu     = blockIdx.z >> 1;
    const int pv     = blockIdx.z & 1;
    const int t    = threadIdx.x;
    const int lane = t & 63;
    const int wg   = t >> 6;
    const int ocb  = octile * 64;
    const int uh0  = uhb * UB;
    __shared__ float xs[ICB][6][66];
    __shared__ float esw[9][ICB][64];
    float acc[UB][16];
    #pragma unroll
    for (int u = 0; u < UB; ++u)
        #pragma unroll
        for (int i = 0; i < 16; ++i) acc[u][i] = 0.f;
    for (int icb = 0; icb < C_IN; icb += ICB) {
        __syncthreads();
        for (int e = t; e < ICB * 6 * 66; e += 256) {
            int col = e % 66; int tmp = e / 66; int row = tmp % 6; int ic = tmp / 6;
            int h = uh0 - 1 + row; int ww = col - 1;
            float v = 0.f;
            if (h >= 0 && h < HW && ww >= 0 && ww < HW)
                v = x[((n * C_IN + icb + ic) * HW + h) * HW + ww];
            xs[ic][row][col] = v;
        }
        for (int e = t; e < 9 * ICB * 64; e += 256) {
            int oc = e & 63; int ic = (e >> 6) & (ICB - 1); int pq = e >> 9;
            esw[pq][ic][oc] = w[(pq * C_IN + icb + ic) * C_OUT + ocb + oc];
        }
        __syncthreads();
        float ereg[18];
        #pragma unroll
        for (int j = 0; j < 18; ++j) {
            int e = t + j * 256; int oc = e & 63; int ic = (e >> 6) & (ICB - 1);
            int tap = e >> 9; int t3 = tap / 3, s3 = tap - t3 * 3;
            int m = 2 * t3 + 1 - pu; int nn = 2 * s3 + 1 - pv;
            float gm0 = Gf(m), gm1 = Gf(m - 1), gm2 = Gf(m - 2);
            float gn0 = Gf(nn), gn1 = Gf(nn - 1), gn2 = Gf(nn - 2);
            float s =
              gm0 * (gn0 * esw[0][ic][oc] + gn1 * esw[1][ic][oc] + gn2 * esw[2][ic][oc])
            + gm1 * (gn0 * esw[3][ic][oc] + gn1 * esw[4][ic][oc] + gn2 * esw[5][ic][oc])
            + gm2 * (gn0 * esw[6][ic][oc] + gn1 * esw[7][ic][oc] + gn2 * esw[8][ic][oc]);
            ereg[j] = s * COEF;
        }
        __syncthreads();
        #pragma unroll
        for (int j = 0; j < 18; ++j) {
            int e = t + j * 256; int oc = e & 63; int ic = (e >> 6) & (ICB - 1);
            int tap = e >> 9;
            esw[tap][ic][oc] = ereg[j];
        }
        __syncthreads();
        for (int ic = 0; ic < ICB; ++ic) {
            #pragma unroll
            for (int t3 = 0; t3 < 3; ++t3) {
                #pragma unroll
                for (int s3 = 0; s3 < 3; ++s3) {
                    const int tap = t3 * 3 + s3;
                    float ev[16];
                    #pragma unroll
                    for (int r = 0; r < 4; ++r)
                        *(float4*)&ev[r * 4] = *(const float4*)&esw[tap][ic][wg * 16 + r * 4];
                    float xv[UB];
                    #pragma unroll
                    for (int u = 0; u < UB; ++u) xv[u] = xs[ic][u + t3][lane + s3];
                    #pragma unroll
                    for (int u = 0; u < UB; ++u)
                        #pragma unroll
                        for (int i = 0; i < 16; ++i) acc[u][i] += xv[u] * ev[i];
                }
            }
        }
    }
    #pragma unroll
    for (int u = 0; u < UB; ++u) {
        int urow = 2 * (uh0 + u) + pu;
        #pragma unroll
        for (int i = 0; i < 16; ++i) {
            int oc = ocb + wg * 16 + i;
            out[((n * C_OUT + oc) * 128 + urow) * 128 + 2 * lane + pv] = acc[u][i];
        }
    }
}

extern "C" void kernel_launch(void* const* d_in, const int* in_sizes, int n_in,
                              void* d_out, int out_size, void* d_ws, size_t ws_size,
                              hipStream_t stream) {
    const float* x = (const float*)d_in[0];   // (8,512,64,64) fp32
    const float* w = (const float*)d_in[1];   // (3,3,512,512) fp32 HWIO
    float* out = (float*)d_out;               // (8,512,128,128) fp32

    if (ws_size >= WS_NEED) {
        short* ews = (short*)d_ws;
        short* xtp = (short*)((char*)d_ws + E_WS_BYTES);
        prep_e_kernel<<<4608, 256, 0, stream>>>(w, ews);
        xpose_kernel<<<4224, 256, 0, stream>>>(x, xtp);
        conv_mfma_kernel<<<2048, 256, 0, stream>>>(xtp, ews, out);
    } else {
        dim3 grid(8, 128, 4);
        conv_par_kernel<<<grid, 256, 0, stream>>>(x, w, out);
    }
}

// Round 8
// 541.302 us; speedup vs baseline: 1.1400x; 1.1400x over previous
//
#include <hip/hip_runtime.h>
#include <stdint.h>

#define AS1 __attribute__((address_space(1)))
#define AS3 __attribute__((address_space(3)))

typedef short v8s  __attribute__((ext_vector_type(8)));
typedef float v4f  __attribute__((ext_vector_type(4)));
typedef float v16f __attribute__((ext_vector_type(16)));

#define C_IN  512
#define C_OUT 512
#define HW    64
#define COEF  9.20711955e-04f   // 1 / (16 * sqrt(9*512))

// E ws: [pu(2)][ocb(16)][ph(32)] chunks of [tap(18)][oc(32)][hi(2)][16B] = 18432 B
#define E_PH_SHORTS 9216
#define E_WS_BYTES  (2u*16u*32u*18432u)               // 18,874,368
// x ws: [n(8)][hp(66)][ph(32)][wp(66)][hi(2)][16B]  (8 ic per 16B unit)
#define XT_BYTES    ((size_t)8*66*66*512*2)           // 35,684,352
#define WS_NEED     ((size_t)E_WS_BYTES + XT_BYTES)

// LDS single buffer: E [18][32][2]x16B = 18432 | x [18 rows][34 cols][2]x16B = 19584
#define XOFF      18432
#define LDS_BYTES 38016

__device__ __forceinline__ float Gf(int i) {
    return (i < 0 || i > 3) ? 0.f : ((i == 1 || i == 2) ? 3.f : 1.f);
}
__device__ __forceinline__ short f2bf(float f) {
    uint32_t u = __float_as_uint(f);
    u += 0x7fffu + ((u >> 16) & 1u);
    return (short)(u >> 16);
}

// ---------------- precompute: x -> [n][hp][ph][wp][hi] bf16 via LDS transpose ---
__global__ __launch_bounds__(256) void xpose_kernel(const float* __restrict__ x,
                                                    short* __restrict__ xt) {
    const int b     = blockIdx.x;
    const int icb64 = b & 7;
    const int hp    = (b >> 3) % 66;
    const int n     = (b >> 3) / 66;
    const int t     = threadIdx.x;

    __shared__ short tile[64][80];   // [w][ic_local]

    const bool hvalid = (hp >= 1 && hp <= 64);
    if (hvalid) {
        #pragma unroll
        for (int r = 0; r < 4; ++r) {
            const int i  = (t >> 4) + r * 16;     // ic_local 0..63
            const int w0 = (t & 15) * 4;          // w 0..63
            const float* src = x + ((size_t)(n * C_IN + icb64 * 64 + i) * HW + (hp - 1)) * HW + w0;
            float4 v = *(const float4*)src;
            tile[w0 + 0][i] = f2bf(v.x);
            tile[w0 + 1][i] = f2bf(v.y);
            tile[w0 + 2][i] = f2bf(v.z);
            tile[w0 + 3][i] = f2bf(v.w);
        }
    }
    __syncthreads();

    // 4 lph x 66 wp x 2 hi = 528 units of 16B
    for (int u = t; u < 528; u += 256) {
        const int hi = u & 1;
        const int wq = u >> 1;
        const int wp = wq % 66;
        const int lph = wq / 66;
        v8s o = (v8s)0;
        if (hvalid && wp >= 1 && wp <= 64)
            o = *(const v8s*)&tile[wp - 1][lph * 16 + hi * 8];
        const int ph = icb64 * 4 + lph;
        *(v8s*)(xt + (((size_t)(n * 66 + hp) * 32 + ph) * 66 + wp) * 16 + hi * 8) = o;
    }
}

// ---------------- precompute: E image, 16-ic phase chunks, dense layout ---------
__global__ __launch_bounds__(256) void prep_e_kernel(const float* __restrict__ w,
                                                     short* __restrict__ ews) {
    int u = blockIdx.x * 256 + threadIdx.x;   // 1,179,648 units of 16B
    int hi   = u & 1;
    int oc_l = (u >> 1) & 31;
    int tap  = (u >> 6) % 18;
    int rest = (u >> 6) / 18;                  // ph + 32*(ocb + 16*pu)
    int ph   = rest & 31;
    int ocb  = (rest >> 5) & 15;
    int pu   = rest >> 9;
    int pv   = tap & 1;
    int ts   = tap >> 1;
    int tt   = ts / 3, ss = ts - tt * 3;
    int m    = 2 * tt + 1 - pu;
    int nn   = 2 * ss + 1 - pv;
    int ic0  = ph * 16 + hi * 8;
    int oc   = ocb * 32 + oc_l;

    v8s o;
    #pragma unroll
    for (int j = 0; j < 8; ++j) {
        float acc = 0.f;
        #pragma unroll
        for (int p = 0; p < 3; ++p) {
            float gm = Gf(m - p);
            if (gm != 0.f) {
                #pragma unroll
                for (int q = 0; q < 3; ++q) {
                    float gn = Gf(nn - q);
                    if (gn != 0.f)
                        acc += gm * gn * w[((size_t)(p * 3 + q) * C_IN + ic0 + j) * C_OUT + oc];
                }
            }
        }
        o[j] = f2bf(acc * COEF);
    }
    *(v8s*)(ews + (size_t)u * 8) = o;
}

// ---------------- main MFMA kernel (32x32x16, dense reads, 16-ic phases) --------
__global__ __launch_bounds__(256) void conv_mfma_kernel(const short* __restrict__ xt,
                                                        const short* __restrict__ ews,
                                                        float* __restrict__ out) {
    int bid  = blockIdx.x;
    int wgid = (bid & 7) * 256 + (bid >> 3);   // bijective XCD swizzle (2048 % 8 == 0)
    int vhb = wgid & 1;  wgid >>= 1;
    int uhb = wgid & 3;  wgid >>= 2;
    int n   = wgid & 7;  wgid >>= 3;
    int ocb = wgid & 15; wgid >>= 4;
    int pu  = wgid;
    const int uh0 = uhb * 16, vh0 = vhb * 32;

    __shared__ char lds_raw[LDS_BYTES];
    AS3 char* lds3 = (AS3 char*)lds_raw;

    const int tid  = threadIdx.x;
    const int lane = tid & 63;
    const int wid  = tid >> 6;      // wave's uh-quarter (0..3)
    const int l31  = lane & 31;
    const int hi   = lane >> 5;

    // E stage source base (chunk for this (pu,ocb), + per-thread 16B unit)
    const short* ebase = ews + (size_t)((pu * 16 + ocb) * 32) * E_PH_SHORTS + (size_t)tid * 8;
    // x stage source base at ph=0 (this block's tile origin)
    const short* xbase = xt + ((size_t)(n * 66 + uh0) * 32 * 66 + vh0) * 16;
    // x units: j in [0,1224): row = j/68, (wp,hi) = (j%68)>>1, (j%68)&1
    // short offset = row*33792 + wp*16 + hi*8 ; per-phase add 1056 shorts
    int xoff[6], xdst[6];
    #pragma unroll
    for (int k = 0; k < 6; ++k) {
        int j;
        if (k == 0)      j = tid - 128;            // active when tid >= 128
        else if (k == 5) j = 1152 + tid;           // active when tid < 72
        else             j = 128 + (k - 1) * 256 + tid;
        if (j < 0 || j >= 1224) j = 0;
        const int r  = j / 68;
        const int rr = j - r * 68;
        xoff[k] = r * 33792 + (rr >> 1) * 16 + (rr & 1) * 8;
        xdst[k] = XOFF + j * 16;
    }

    v16f acc[4][2];   // [u][pv]
    #pragma unroll
    for (int u = 0; u < 4; ++u)
        #pragma unroll
        for (int pv = 0; pv < 2; ++pv)
            acc[u][pv] = (v16f)0.f;

    #pragma unroll 1
    for (int ph = 0; ph < 32; ++ph) {
        __syncthreads();   // all waves done reading previous phase's tiles

        // ---- stage E (linear 18432B copy) + x (dense per-row slices) ----
        const short* ep = ebase + (size_t)ph * E_PH_SHORTS;
        const short* xp = xbase + (size_t)ph * 1056;
        #pragma unroll
        for (int it = 0; it < 4; ++it)
            __builtin_amdgcn_global_load_lds((const AS1 void*)(ep + it * 2048),
                (AS3 void*)(lds3 + it * 4096 + tid * 16), 16, 0, 0);
        if (tid < 128)
            __builtin_amdgcn_global_load_lds((const AS1 void*)(ep + 8192),
                (AS3 void*)(lds3 + 16384 + tid * 16), 16, 0, 0);
        else
            __builtin_amdgcn_global_load_lds((const AS1 void*)(xp + xoff[0]),
                (AS3 void*)(lds3 + xdst[0]), 16, 0, 0);
        #pragma unroll
        for (int k = 1; k < 5; ++k)
            __builtin_amdgcn_global_load_lds((const AS1 void*)(xp + xoff[k]),
                (AS3 void*)(lds3 + xdst[k]), 16, 0, 0);
        if (tid < 72)
            __builtin_amdgcn_global_load_lds((const AS1 void*)(xp + xoff[5]),
                (AS3 void*)(lds3 + xdst[5]), 16, 0, 0);

        __syncthreads();   // compiler emits vmcnt(0) drain before this

        // ---- compute: dense 1KB reads; 36 ds_read_b128 feed 72 MFMA ----
        #pragma unroll
        for (int s = 0; s < 3; ++s) {
            const int c = l31 + s;
            v8s A[6];
            #pragma unroll
            for (int rr = 0; rr < 6; ++rr)
                A[rr] = *(const v8s*)(lds_raw + XOFF
                         + (((wid * 4 + rr) * 34 + c) * 2 + hi) * 16);
            #pragma unroll
            for (int t = 0; t < 3; ++t) {
                #pragma unroll
                for (int pv = 0; pv < 2; ++pv) {
                    v8s B = *(const v8s*)(lds_raw
                             + ((((t * 3 + s) * 2 + pv) * 32 + l31) * 2 + hi) * 16);
                    #pragma unroll
                    for (int u = 0; u < 4; ++u)
                        acc[u][pv] = __builtin_amdgcn_mfma_f32_32x32x16_bf16(
                                         A[u + t], B, acc[u][pv], 0, 0, 0);
                }
            }
        }
    }

    // epilogue: D col = lane&31 (oc), row = (reg&3) + 8*(reg>>2) + 4*(lane>>5) (vh)
    const int oc_g = ocb * 32 + l31;
    float* ob = out + ((size_t)(n * C_OUT + oc_g)) * 128 * 128;
    #pragma unroll
    for (int u = 0; u < 4; ++u) {
        const int h = 2 * (uh0 + wid * 4 + u) + pu;
        #pragma unroll
        for (int rg = 0; rg < 8; ++rg) {
            const int reg  = rg * 2;
            const int vh_l = (reg & 3) + 8 * (reg >> 2) + 4 * hi;
            v4f f;
            f[0] = acc[u][0][reg];
            f[1] = acc[u][1][reg];
            f[2] = acc[u][0][reg + 1];
            f[3] = acc[u][1][reg + 1];
            *(v4f*)(ob + (size_t)h * 128 + 2 * (vh0 + vh_l)) = f;
        }
    }
}

// ---------------- fallback (validated round-1 VALU kernel) ----------------------
#define ICB 8
#define UB  4
__global__ __launch_bounds__(256) void conv_par_kernel(
        const float* __restrict__ x, const float* __restrict__ w,
        float* __restrict__ out) {
    const int octile = blockIdx.x;
    const int n      = blockIdx.y >> 4;
    const int uhb    = blockIdx.y & 15;
    const int pu     = blockIdx.z >> 1;
    const int pv     = blockIdx.z & 1;
    const int t    = threadIdx.x;
    const int lane = t & 63;
    const int wg   = t >> 6;
    const int ocb  = octile * 64;
    const int uh0  = uhb * UB;
    __shared__ float xs[ICB][6][66];
    __shared__ float esw[9][ICB][64];
    float acc[UB][16];
    #pragma unroll
    for (int u = 0; u < UB; ++u)
        #pragma unroll
        for (int i = 0; i < 16; ++i) acc[u][i] = 0.f;
    for (int icb = 0; icb < C_IN; icb += ICB) {
        __syncthreads();
        for (int e = t; e < ICB * 6 * 66; e += 256) {
            int col = e % 66; int tmp = e / 66; int row = tmp % 6; int ic = tmp / 6;
            int h = uh0 - 1 + row; int ww = col - 1;
            float v = 0.f;
            if (h >= 0 && h < HW && ww >= 0 && ww < HW)
                v = x[((n * C_IN + icb + ic) * HW + h) * HW + ww];
            xs[ic][row][col] = v;
        }
        for (int e = t; e < 9 * ICB * 64; e += 256) {
            int oc = e & 63; int ic = (e >> 6) & (ICB - 1); int pq = e >> 9;
            esw[pq][ic][oc] = w[(pq * C_IN + icb + ic) * C_OUT + ocb + oc];
        }
        __syncthreads();
        float ereg[18];
        #pragma unroll
        for (int j = 0; j < 18; ++j) {
            int e = t + j * 256; int oc = e & 63; int ic = (e >> 6) & (ICB - 1);
            int tap = e >> 9; int t3 = tap / 3, s3 = tap - t3 * 3;
            int m = 2 * t3 + 1 - pu; int nn = 2 * s3 + 1 - pv;
            float gm0 = Gf(m), gm1 = Gf(m - 1), gm2 = Gf(m - 2);
            float gn0 = Gf(nn), gn1 = Gf(nn - 1), gn2 = Gf(nn - 2);
            float s =
              gm0 * (gn0 * esw[0][ic][oc] + gn1 * esw[1][ic][oc] + gn2 * esw[2][ic][oc])
            + gm1 * (gn0 * esw[3][ic][oc] + gn1 * esw[4][ic][oc] + gn2 * esw[5][ic][oc])
            + gm2 * (gn0 * esw[6][ic][oc] + gn1 * esw[7][ic][oc] + gn2 * esw[8][ic][oc]);
            ereg[j] = s * COEF;
        }
        __syncthreads();
        #pragma unroll
        for (int j = 0; j < 18; ++j) {
            int e = t + j * 256; int oc = e & 63; int ic = (e >> 6) & (ICB - 1);
            int tap = e >> 9;
            esw[tap][ic][oc] = ereg[j];
        }
        __syncthreads();
        for (int ic = 0; ic < ICB; ++ic) {
            #pragma unroll
            for (int t3 = 0; t3 < 3; ++t3) {
                #pragma unroll
                for (int s3 = 0; s3 < 3; ++s3) {
                    const int tap = t3 * 3 + s3;
                    float ev[16];
                    #pragma unroll
                    for (int r = 0; r < 4; ++r)
                        *(float4*)&ev[r * 4] = *(const float4*)&esw[tap][ic][wg * 16 + r * 4];
                    float xv[UB];
                    #pragma unroll
                    for (int u = 0; u < UB; ++u) xv[u] = xs[ic][u + t3][lane + s3];
                    #pragma unroll
                    for (int u = 0; u < UB; ++u)
                        #pragma unroll
                        for (int i = 0; i < 16; ++i) acc[u][i] += xv[u] * ev[i];
                }
            }
        }
    }
    #pragma unroll
    for (int u = 0; u < UB; ++u) {
        int urow = 2 * (uh0 + u) + pu;
        #pragma unroll
        for (int i = 0; i < 16; ++i) {
            int oc = ocb + wg * 16 + i;
            out[((n * C_OUT + oc) * 128 + urow) * 128 + 2 * lane + pv] = acc[u][i];
        }
    }
}

extern "C" void kernel_launch(void* const* d_in, const int* in_sizes, int n_in,
                              void* d_out, int out_size, void* d_ws, size_t ws_size,
                              hipStream_t stream) {
    const float* x = (const float*)d_in[0];   // (8,512,64,64) fp32
    const float* w = (const float*)d_in[1];   // (3,3,512,512) fp32 HWIO
    float* out = (float*)d_out;               // (8,512,128,128) fp32

    if (ws_size >= WS_NEED) {
        short* ews = (short*)d_ws;
        short* xtp = (short*)((char*)d_ws + E_WS_BYTES);
        prep_e_kernel<<<4608, 256, 0, stream>>>(w, ews);
        xpose_kernel<<<4224, 256, 0, stream>>>(x, xtp);
        conv_mfma_kernel<<<2048, 256, 0, stream>>>(xtp, ews, out);
    } else {
        dim3 grid(8, 128, 4);
        conv_par_kernel<<<grid, 256, 0, stream>>>(x, w, out);
    }
}